// Round 8
// baseline (611.286 us; speedup 1.0000x reference)
//
#include <hip/hip_runtime.h>

// Sub4BitLinear: y = X[M,K] @ W[N,K]^T, M=8192 N=4096 K=4096
// (1) x f32->bf16, (2) dequant codes->bf16 W, (3) 256x256 8-phase MFMA GEMM
// with phase-skewed ds_reads (read in phase p what phase p+1's MFMA eats).

#define M_DIM 8192
#define N_DIM 4096
#define K_DIM 4096
#define BK 64
#define NKT (K_DIM / BK)   // 64 K-tiles

typedef __attribute__((ext_vector_type(8))) short short8;
typedef __attribute__((ext_vector_type(4))) float f32x4;

#define AS1 __attribute__((address_space(1)))
#define AS3 __attribute__((address_space(3)))

__device__ __forceinline__ unsigned short f2bf(float f) {
    unsigned int u = __builtin_bit_cast(unsigned int, f);
    u += 0x7fffu + ((u >> 16) & 1u);
    return (unsigned short)(u >> 16);
}

__device__ __forceinline__ void gl_lds16(const void* g, void* l) {
    __builtin_amdgcn_global_load_lds((const AS1 void*)g, (AS3 void*)l, 16, 0, 0);
}

// ---------------- kernel 1: x f32 -> bf16 ----------------
__global__ __launch_bounds__(256) void cvt_x(const float4* __restrict__ X,
                                             ushort4* __restrict__ O, int n4) {
    int stride = gridDim.x * blockDim.x;
    for (int i = blockIdx.x * blockDim.x + threadIdx.x; i < n4; i += stride) {
        float4 v = X[i];
        ushort4 o;
        o.x = f2bf(v.x); o.y = f2bf(v.y); o.z = f2bf(v.z); o.w = f2bf(v.w);
        O[i] = o;
    }
}

// ---------------- kernel 2: dequant codes -> bf16 W ----------------
__global__ __launch_bounds__(256) void dequant(const int* __restrict__ CD,
                                               const float* __restrict__ G,
                                               ushort* __restrict__ W) {
    const int o = blockIdx.x;
    __shared__ ushort gs[8];
    if (threadIdx.x < 8) gs[threadIdx.x] = f2bf(G[o * 8 + threadIdx.x]);
    __syncthreads();
    const int4* cp = (const int4*)(CD + (size_t)o * K_DIM);
    ushort4* wp = (ushort4*)(W + (size_t)o * K_DIM);
#pragma unroll
    for (int r = 0; r < 4; ++r) {
        int idx = r * 256 + threadIdx.x;
        int4 c = cp[idx];
        ushort4 w;
        w.x = gs[c.x]; w.y = gs[c.y]; w.z = gs[c.z]; w.w = gs[c.w];
        wp[idx] = w;
    }
}

// ---------------- kernel 3: 256x256 8-phase skewed-read bf16 MFMA GEMM ----------------
// 512 threads = 8 waves (2M x 4N); per-wave output 128x64 = acc[8][4] frags.
// LDS: [buf][half][128 x 64] A and B, XOR-swizzled (elem ^= (row&7)<<3).
// Read skew: p8'->faL/fbL(e), p1->fbH(e), p2->faH(e), p4->faL/fbL(o),
// p5->fbH(o), p6->faH(o), p8->faL/fbL(e2). Each phase's read drain overlaps
// the current quadrant's MFMA. Publishes: vmcnt(2)+barrier at end-p3 (tile o)
// and end-p7 (tile e2); stages: p1 o.A1 | p3 e2.B0 | p4 e2.B1 | p5 e2.A0 |
// p6 e2.A1 | p7 o2.B0 | p8 o2.B1,o2.A0. FIFO induction: each ENDW leaves
// exactly the just-issued B0 (2 loads) outstanding.
__global__ __launch_bounds__(512, 2) void gemm8(const ushort* __restrict__ A,
                                                const ushort* __restrict__ B,
                                                float* __restrict__ C) {
    __shared__ ushort As[2][2][128 * 64];
    __shared__ ushort Bs[2][2][128 * 64];

    const int tid = threadIdx.x;
    const int lane = tid & 63;
    const int wid = tid >> 6;
    const int wm = wid >> 2;        // 0..1: wave's M half of the 256 tile
    const int wn = wid & 3;         // 0..3: wave's N slice
    const int bh = wn >> 1;         // B half-buffer

    // XCD-bijective block swizzle (nwg = 512, %8 == 0)
    int wg = blockIdx.x;
    wg = (wg & 7) * (gridDim.x >> 3) + (wg >> 3);
    const int ntn = N_DIM / 256;    // 16
    const int bm = (wg / ntn) * 256;
    const int bn = (wg % ntn) * 256;

    // fragment read lane constants:
    // elem = quad_off(static) + offk{ks};  offk = fr*64 + ((ks*32+fkc)^swz)
    const int fr = lane & 15;
    const int fkc = (lane >> 4) << 3;           // 0,8,16,24
    const int swz = (fr & 7) << 3;
    const int offk0 = fr * 64 + (fkc ^ (swz & 24)) + (swz & 32);
    const int offk1 = offk0 ^ 32;
    const int bwoff = (wn & 1) * 4096;          // B wave row-base (elements)

    // staging: chunk c = tid; row=c>>3 (+64 for 2nd instr), slot=(c&7)^(row&7)
    const int row0 = tid >> 3;                  // 0..63
    const int sl = (((tid & 7) ^ (row0 & 7)) << 3);

#define STG(GP, RB, KT, LD) do {                                                   \
        const int ks_ = (((KT) < NKT) ? (KT) : 0) * BK;                            \
        gl_lds16((GP) + (size_t)((RB) + row0) * K_DIM + ks_ + sl,                  \
                 (LD) + wid * 512);                                                \
        gl_lds16((GP) + (size_t)((RB) + row0 + 64) * K_DIM + ks_ + sl,             \
                 (LD) + 4096 + wid * 512);                                         \
    } while (0)

#define RD_A(B_, MH_)                                                              \
    _Pragma("unroll") for (int m = 0; m < 4; ++m) {                                \
        fa[(MH_) * 4 + m][0] = *(const short8*)&As[B_][wm][(MH_) * 4096 + m * 1024 + offk0]; \
        fa[(MH_) * 4 + m][1] = *(const short8*)&As[B_][wm][(MH_) * 4096 + m * 1024 + offk1]; \
    }

#define RD_B(B_, NH_)                                                              \
    _Pragma("unroll") for (int n = 0; n < 2; ++n) {                                \
        fb[(NH_) * 2 + n][0] = *(const short8*)&Bs[B_][bh][bwoff + (NH_) * 2048 + n * 1024 + offk0]; \
        fb[(NH_) * 2 + n][1] = *(const short8*)&Bs[B_][bh][bwoff + (NH_) * 2048 + n * 1024 + offk1]; \
    }

// ks-outer: 8 independent accumulators between dependent MFMA pairs
#define MF(MH_, NH_)                                                               \
    _Pragma("unroll") for (int ks = 0; ks < 2; ++ks)                               \
    _Pragma("unroll") for (int m = 0; m < 4; ++m)                                  \
    _Pragma("unroll") for (int n = 0; n < 2; ++n)                                  \
        acc[(MH_) * 4 + m][(NH_) * 2 + n] = __builtin_amdgcn_mfma_f32_16x16x32_bf16( \
            fa[(MH_) * 4 + m][ks], fb[(NH_) * 2 + n][ks],                          \
            acc[(MH_) * 4 + m][(NH_) * 2 + n], 0, 0, 0);

#define PH_MID                                                                     \
    __builtin_amdgcn_s_setprio(1);

#define PH_END                                                                     \
    __builtin_amdgcn_s_setprio(0);                                                 \
    __builtin_amdgcn_sched_barrier(0);                                             \
    __builtin_amdgcn_s_barrier();

#define PH_ENDW                                                                    \
    __builtin_amdgcn_s_setprio(0);                                                 \
    __builtin_amdgcn_sched_barrier(0);                                             \
    asm volatile("s_waitcnt vmcnt(2)" ::: "memory");                               \
    __builtin_amdgcn_s_barrier();

    f32x4 acc[8][4] = {};
    short8 fa[8][2];
    short8 fb[4][2];

    // prologue: tile0 {B0,B1,A0,A1}; tile1 {B0,B1,A0}. vmcnt(6) -> tile0
    // resident; pre-read faL/fbL(t0) to feed p1's MFMA.
    STG(B, bn,       0, &Bs[0][0][0]);
    STG(B, bn + 128, 0, &Bs[0][1][0]);
    STG(A, bm,       0, &As[0][0][0]);
    STG(A, bm + 128, 0, &As[0][1][0]);
    STG(B, bn,       1, &Bs[1][0][0]);
    STG(B, bn + 128, 1, &Bs[1][1][0]);
    STG(A, bm,       1, &As[1][0][0]);
    asm volatile("s_waitcnt vmcnt(6)" ::: "memory");
    __builtin_amdgcn_s_barrier();
    RD_A(0, 0) RD_B(0, 0)

    for (int j = 0; j < NKT / 2; ++j) {
        const int o = 2 * j + 1, e2 = 2 * j + 2, o2 = 2 * j + 3;
        // p1: read fbH(e); stage o.A1 -> As[1][1]
        RD_B(0, 1)
        STG(A, bm + 128, o, &As[1][1][0]);
        PH_MID MF(0, 0) PH_END
        // p2: read faH(e)
        RD_A(0, 1)
        PH_MID MF(0, 1) PH_END
        // p3: stage e2.B0; vmcnt(2) -> tile o (B0,B1,A0 from prev iter + A1
        // from p1) fully resident
        STG(B, bn, e2, &Bs[0][0][0]);
        PH_MID MF(1, 0) PH_ENDW
        // p4: read faL(o), fbL(o); stage e2.B1
        RD_A(1, 0) RD_B(1, 0)
        STG(B, bn + 128, e2, &Bs[0][1][0]);
        PH_MID MF(1, 1) PH_END
        // p5: read fbH(o); stage e2.A0
        RD_B(1, 1)
        STG(A, bm, e2, &As[0][0][0]);
        PH_MID MF(0, 0) PH_END
        // p6: read faH(o); stage e2.A1
        RD_A(1, 1)
        STG(A, bm + 128, e2, &As[0][1][0]);
        PH_MID MF(0, 1) PH_END
        // p7: stage o2.B0; vmcnt(2) -> tile e2 fully resident
        STG(B, bn, o2, &Bs[1][0][0]);
        PH_MID MF(1, 0) PH_ENDW
        // p8: read faL(e2), fbL(e2); stage o2.B1, o2.A0
        RD_A(0, 0) RD_B(0, 0)
        STG(B, bn + 128, o2, &Bs[1][1][0]);
        STG(A, bm, o2, &As[1][0][0]);
        PH_MID MF(1, 1) PH_END
    }
    asm volatile("s_waitcnt vmcnt(0)" ::: "memory");

    // C-write: row = (lane>>4)*4 + r, col = lane&15 within each 16x16 frag
    const int crow0 = bm + wm * 128 + ((lane >> 4) << 2);
    const int ccol0 = bn + wn * 64 + (lane & 15);
#pragma unroll
    for (int mi = 0; mi < 8; ++mi)
#pragma unroll
        for (int ni = 0; ni < 4; ++ni)
#pragma unroll
            for (int r = 0; r < 4; ++r)
                C[(size_t)(crow0 + mi * 16 + r) * N_DIM + ccol0 + ni * 16] = acc[mi][ni][r];
}

// ---------------- fallback: tiled f32 GEMM with on-the-fly dequant ----------------
__global__ __launch_bounds__(256) void fb_gemm(const float* __restrict__ X,
                                               const float* __restrict__ G,
                                               const int* __restrict__ CD,
                                               float* __restrict__ Y) {
    __shared__ float xs[16][64];
    __shared__ float ws[16][64];
    const int bm = blockIdx.y << 6, bn = blockIdx.x << 6;
    const int tid = threadIdx.x;
    const int tn = tid & 15, tm = tid >> 4;
    float acc[4][4] = {};
    for (int k0 = 0; k0 < K_DIM; k0 += 16) {
#pragma unroll
        for (int r = 0; r < 4; ++r) {
            int e = r * 256 + tid;
            int mm = e >> 4, kk = e & 15;
            xs[kk][mm] = X[(size_t)(bm + mm) * K_DIM + k0 + kk];
            int code = CD[(size_t)(bn + mm) * K_DIM + k0 + kk];
            ws[kk][mm] = G[(bn + mm) * 8 + code];
        }
        __syncthreads();
#pragma unroll
        for (int kk = 0; kk < 16; ++kk)
#pragma unroll
            for (int i = 0; i < 4; ++i)
#pragma unroll
                for (int j = 0; j < 4; ++j)
                    acc[i][j] += xs[kk][tm * 4 + i] * ws[kk][tn * 4 + j];
        __syncthreads();
    }
#pragma unroll
    for (int i = 0; i < 4; ++i)
#pragma unroll
        for (int j = 0; j < 4; ++j)
            Y[(size_t)(bm + tm * 4 + i) * N_DIM + bn + tn * 4 + j] = acc[i][j];
}

extern "C" void kernel_launch(void* const* d_in, const int* in_sizes, int n_in,
                              void* d_out, int out_size, void* d_ws, size_t ws_size,
                              hipStream_t stream) {
    const float* x = (const float*)d_in[0];
    const float* qg = (const float*)d_in[1];
    const int* wc = (const int*)d_in[2];
    float* y = (float*)d_out;

    const size_t xb_elems = (size_t)M_DIM * K_DIM;
    const size_t wb_elems = (size_t)N_DIM * K_DIM;
    const size_t need = (xb_elems + wb_elems) * sizeof(ushort);

    if (ws_size >= need) {
        ushort* xb = (ushort*)d_ws;
        ushort* wb = xb + xb_elems;
        const int n4 = (int)(xb_elems / 4);
        hipLaunchKernelGGL(cvt_x, dim3(2048), dim3(256), 0, stream,
                           (const float4*)x, (ushort4*)xb, n4);
        hipLaunchKernelGGL(dequant, dim3(N_DIM), dim3(256), 0, stream, wc, qg, wb);
        const int nwg = (M_DIM / 256) * (N_DIM / 256);   // 512
        hipLaunchKernelGGL(gemm8, dim3(nwg), dim3(512), 0, stream,
                           xb, wb, y);
    } else {
        hipLaunchKernelGGL(fb_gemm, dim3(N_DIM / 64, M_DIM / 64), dim3(256), 0, stream,
                           x, qg, wc, y);
    }
}

// Round 9
// 182.197 us; speedup vs baseline: 3.3551x; 3.3551x over previous
//
#include <hip/hip_runtime.h>

// Sub4BitLinear: y = X[M,K] @ W[N,K]^T, M=8192 N=4096 K=4096
// int8 path: (1) per-row quant x -> i8 + sx, (2) per-row quant codebook W -> i8 + sw,
// (3) 256x256 8-phase i8 MFMA GEMM (i32 exact accum), epilogue y = acc*sx[m]*sw[n].

#define M_DIM 8192
#define N_DIM 4096
#define K_DIM 4096
#define BK 128              // i8 elements per K-tile (128 B/row, same bytes as 64 bf16)
#define NKT (K_DIM / BK)    // 32 K-tiles

typedef __attribute__((ext_vector_type(4))) int int32x4;

#define AS1 __attribute__((address_space(1)))
#define AS3 __attribute__((address_space(3)))

__device__ __forceinline__ void gl_lds16(const void* g, void* l) {
    __builtin_amdgcn_global_load_lds((const AS1 void*)g, (AS3 void*)l, 16, 0, 0);
}

// ---------------- kernel 1: per-row quantize x -> int8 ----------------
__global__ __launch_bounds__(256) void quant_x(const float* __restrict__ X,
                                               char* __restrict__ XQ,
                                               float* __restrict__ SX) {
    const int row = blockIdx.x;
    const int t = threadIdx.x;
    const float4* xp = (const float4*)(X + (size_t)row * K_DIM);
    float4 v[4];
    float mx = 0.0f;
#pragma unroll
    for (int i = 0; i < 4; ++i) {
        v[i] = xp[t * 4 + i];
        mx = fmaxf(mx, fmaxf(fmaxf(fabsf(v[i].x), fabsf(v[i].y)),
                             fmaxf(fabsf(v[i].z), fabsf(v[i].w))));
    }
#pragma unroll
    for (int off = 1; off < 64; off <<= 1)
        mx = fmaxf(mx, __shfl_xor(mx, off));
    __shared__ float wmx[4];
    if ((t & 63) == 0) wmx[t >> 6] = mx;
    __syncthreads();
    mx = fmaxf(fmaxf(wmx[0], wmx[1]), fmaxf(wmx[2], wmx[3]));
    const float inv = 127.0f / mx;
    int4 o4;
    int* po = (int*)&o4;
#pragma unroll
    for (int i = 0; i < 4; ++i) {
        int q0 = (int)rintf(v[i].x * inv);
        int q1 = (int)rintf(v[i].y * inv);
        int q2 = (int)rintf(v[i].z * inv);
        int q3 = (int)rintf(v[i].w * inv);
        po[i] = (q0 & 255) | ((q1 & 255) << 8) | ((q2 & 255) << 16) | ((q3 & 255) << 24);
    }
    ((int4*)(XQ + (size_t)row * K_DIM))[t] = o4;
    if (t == 0) SX[row] = mx * (1.0f / 127.0f);
}

// ---------------- kernel 2: per-row quantize codebook W -> int8 ----------------
__global__ __launch_bounds__(256) void quant_w(const int* __restrict__ CD,
                                               const float* __restrict__ G,
                                               char* __restrict__ WQ,
                                               float* __restrict__ SW) {
    const int o = blockIdx.x;
    __shared__ int gq[8];
    if (threadIdx.x == 0) {
        float g[8], mx = 0.0f;
#pragma unroll
        for (int j = 0; j < 8; ++j) { g[j] = G[o * 8 + j]; mx = fmaxf(mx, fabsf(g[j])); }
        mx = fmaxf(mx, 1e-20f);
        const float inv = 127.0f / mx;
        SW[o] = mx * (1.0f / 127.0f);
#pragma unroll
        for (int j = 0; j < 8; ++j) gq[j] = ((int)rintf(g[j] * inv)) & 255;
    }
    __syncthreads();
    const int4* cp = (const int4*)(CD + (size_t)o * K_DIM);
    int* wp = (int*)(WQ + (size_t)o * K_DIM);
#pragma unroll
    for (int r = 0; r < 4; ++r) {
        int idx = r * 256 + threadIdx.x;
        int4 c = cp[idx];
        wp[idx] = gq[c.x] | (gq[c.y] << 8) | (gq[c.z] << 16) | (gq[c.w] << 24);
    }
}

// ---------------- kernel 3: 256x256 8-phase i8 MFMA GEMM ----------------
// Byte-identical port of the best bf16 schedule: 512 threads = 8 waves (2M x 4N),
// per-wave output 128x64 = acc[8][4] frags of 16x16 (i32). LDS [buf][half][128x128B],
// XOR-swizzled (byte ^= (row&7)<<4). mfma_i32_16x16x64_i8, 2 ks-slices per phase
// (K=128/tile). Same staging/vmcnt(6) schedule; one barrier per phase.
__global__ __launch_bounds__(512, 2) void gemm8(const char* __restrict__ A,
                                                const char* __restrict__ B,
                                                const float* __restrict__ SX,
                                                const float* __restrict__ SW,
                                                float* __restrict__ C) {
    __shared__ char As[2][2][128 * 128];
    __shared__ char Bs[2][2][128 * 128];

    const int tid = threadIdx.x;
    const int lane = tid & 63;
    const int wid = tid >> 6;
    const int wm = wid >> 2;        // 0..1: wave's M half
    const int wn = wid & 3;         // 0..3: wave's N slice
    const int bh = wn >> 1;         // B half-buffer

    // XCD-bijective block swizzle (nwg = 512, %8 == 0)
    int wg = blockIdx.x;
    wg = (wg & 7) * (gridDim.x >> 3) + (wg >> 3);
    const int ntn = N_DIM / 256;    // 16
    const int bm = (wg / ntn) * 256;
    const int bn = (wg % ntn) * 256;

    // fragment read lane constants (byte units):
    const int fr = lane & 15;
    const int swzb = (fr & 7) << 4;
    const int offk0 = fr * 128 + (((lane >> 4) << 4) ^ swzb);
    const int offk1 = offk0 ^ 64;
    const int bwoffB = (wn & 1) * 8192;

    // staging: chunk c = q*512 + tid; row=c>>3, slot=(c&7)^(row&7) (16B slots)
    const int row0 = tid >> 3;                  // 0..63
    const int sl = (((tid & 7) ^ (row0 & 7)) << 4);

#define STG(GP, RB, KT, LD) do {                                                   \
        const int kb_ = (((KT) < NKT) ? (KT) : 0) * BK;                            \
        gl_lds16((GP) + (size_t)((RB) + row0) * K_DIM + kb_ + sl,                  \
                 (LD) + wid * 1024);                                               \
        gl_lds16((GP) + (size_t)((RB) + row0 + 64) * K_DIM + kb_ + sl,             \
                 (LD) + 8192 + wid * 1024);                                        \
    } while (0)

#define RD_A(B_, MH_)                                                              \
    _Pragma("unroll") for (int m = 0; m < 4; ++m) {                                \
        fa[(MH_) * 4 + m][0] = *(const int32x4*)&As[B_][wm][(MH_) * 8192 + m * 2048 + offk0]; \
        fa[(MH_) * 4 + m][1] = *(const int32x4*)&As[B_][wm][(MH_) * 8192 + m * 2048 + offk1]; \
    }

#define RD_B(B_, NH_)                                                              \
    _Pragma("unroll") for (int n = 0; n < 2; ++n) {                                \
        fb[(NH_) * 2 + n][0] = *(const int32x4*)&Bs[B_][bh][bwoffB + (NH_) * 4096 + n * 2048 + offk0]; \
        fb[(NH_) * 2 + n][1] = *(const int32x4*)&Bs[B_][bh][bwoffB + (NH_) * 4096 + n * 2048 + offk1]; \
    }

// ks-outer: 8 independent accumulators between dependent MFMA pairs
#define MF(MH_, NH_)                                                               \
    _Pragma("unroll") for (int ks = 0; ks < 2; ++ks)                               \
    _Pragma("unroll") for (int m = 0; m < 4; ++m)                                  \
    _Pragma("unroll") for (int n = 0; n < 2; ++n)                                  \
        acc[(MH_) * 4 + m][(NH_) * 2 + n] = __builtin_amdgcn_mfma_i32_16x16x64_i8( \
            fa[(MH_) * 4 + m][ks], fb[(NH_) * 2 + n][ks],                          \
            acc[(MH_) * 4 + m][(NH_) * 2 + n], 0, 0, 0);

#define PH_MID                                                                     \
    __builtin_amdgcn_s_setprio(1);

#define PH_END                                                                     \
    __builtin_amdgcn_s_setprio(0);                                                 \
    __builtin_amdgcn_sched_barrier(0);                                             \
    __builtin_amdgcn_s_barrier();

#define PH_ENDW                                                                    \
    __builtin_amdgcn_s_setprio(0);                                                 \
    __builtin_amdgcn_sched_barrier(0);                                             \
    asm volatile("s_waitcnt vmcnt(6)" ::: "memory");                               \
    __builtin_amdgcn_s_barrier();

    int32x4 acc[8][4] = {};
    int32x4 fa[8][2];
    int32x4 fb[4][2];

    // prologue: tile0 {A0,A1,B0,B1}; tile1 {B0,B1,A0} (steady-state FIFO).
    STG(A, bm,       0, &As[0][0][0]);
    STG(A, bm + 128, 0, &As[0][1][0]);
    STG(B, bn,       0, &Bs[0][0][0]);
    STG(B, bn + 128, 0, &Bs[0][1][0]);
    STG(B, bn,       1, &Bs[1][0][0]);
    STG(B, bn + 128, 1, &Bs[1][1][0]);
    STG(A, bm,       1, &As[1][0][0]);
    asm volatile("s_waitcnt vmcnt(6)" ::: "memory");
    __builtin_amdgcn_s_barrier();

    for (int j = 0; j < NKT / 2; ++j) {
        const int o = 2 * j + 1, e2 = 2 * j + 2, o2 = 2 * j + 3;
        // p1: read e.{A-h0, B-h0}; stage o.A1
        RD_A(0, 0) RD_B(0, 0)
        STG(A, bm + 128, o, &As[1][1][0]);
        PH_MID MF(0, 0) PH_END
        // p2: read e.B-h1; stage e2.B0
        RD_B(0, 1)
        STG(B, bn, e2, &Bs[0][0][0]);
        PH_MID MF(0, 1) PH_END
        // p3: read e.A-h1; stage e2.B1
        RD_A(0, 1)
        STG(B, bn + 128, e2, &Bs[0][1][0]);
        PH_MID MF(1, 0) PH_END
        // p4: stage e2.A0; vmcnt(6) -> tile o fully resident
        STG(A, bm, e2, &As[0][0][0]);
        PH_MID MF(1, 1) PH_ENDW
        // p5: read o.{A-h0, B-h0}; stage e2.A1
        RD_A(1, 0) RD_B(1, 0)
        STG(A, bm + 128, e2, &As[0][1][0]);
        PH_MID MF(0, 0) PH_END
        // p6: read o.B-h1; stage o2.B0
        RD_B(1, 1)
        STG(B, bn, o2, &Bs[1][0][0]);
        PH_MID MF(0, 1) PH_END
        // p7: read o.A-h1; stage o2.B1
        RD_A(1, 1)
        STG(B, bn + 128, o2, &Bs[1][1][0]);
        PH_MID MF(1, 0) PH_END
        // p8: stage o2.A0; vmcnt(6) -> tile e2 fully resident
        STG(A, bm, o2, &As[1][0][0]);
        PH_MID MF(1, 1) PH_ENDW
    }
    asm volatile("s_waitcnt vmcnt(0)" ::: "memory");

    // C-write with scales: row = (lane>>4)*4 + r, col = lane&15 per 16x16 frag
    const int crow0 = bm + wm * 128 + ((lane >> 4) << 2);
    const int ccol0 = bn + wn * 64 + (lane & 15);
    float swc[4];
#pragma unroll
    for (int ni = 0; ni < 4; ++ni) swc[ni] = SW[ccol0 + ni * 16];
#pragma unroll
    for (int mi = 0; mi < 8; ++mi)
#pragma unroll
        for (int r = 0; r < 4; ++r) {
            const float sxr = SX[crow0 + mi * 16 + r];
#pragma unroll
            for (int ni = 0; ni < 4; ++ni)
                C[(size_t)(crow0 + mi * 16 + r) * N_DIM + ccol0 + ni * 16] =
                    (float)acc[mi][ni][r] * sxr * swc[ni];
        }
}

// ---------------- fallback: tiled f32 GEMM with on-the-fly dequant ----------------
__global__ __launch_bounds__(256) void fb_gemm(const float* __restrict__ X,
                                               const float* __restrict__ G,
                                               const int* __restrict__ CD,
                                               float* __restrict__ Y) {
    __shared__ float xs[16][64];
    __shared__ float ws[16][64];
    const int bm = blockIdx.y << 6, bn = blockIdx.x << 6;
    const int tid = threadIdx.x;
    const int tn = tid & 15, tm = tid >> 4;
    float acc[4][4] = {};
    for (int k0 = 0; k0 < K_DIM; k0 += 16) {
#pragma unroll
        for (int r = 0; r < 4; ++r) {
            int e = r * 256 + tid;
            int mm = e >> 4, kk = e & 15;
            xs[kk][mm] = X[(size_t)(bm + mm) * K_DIM + k0 + kk];
            int code = CD[(size_t)(bn + mm) * K_DIM + k0 + kk];
            ws[kk][mm] = G[(bn + mm) * 8 + code];
        }
        __syncthreads();
#pragma unroll
        for (int kk = 0; kk < 16; ++kk)
#pragma unroll
            for (int i = 0; i < 4; ++i)
#pragma unroll
                for (int j = 0; j < 4; ++j)
                    acc[i][j] += xs[kk][tm * 4 + i] * ws[kk][tn * 4 + j];
        __syncthreads();
    }
#pragma unroll
    for (int i = 0; i < 4; ++i)
#pragma unroll
        for (int j = 0; j < 4; ++j)
            Y[(size_t)(bm + tm * 4 + i) * N_DIM + bn + tn * 4 + j] = acc[i][j];
}

extern "C" void kernel_launch(void* const* d_in, const int* in_sizes, int n_in,
                              void* d_out, int out_size, void* d_ws, size_t ws_size,
                              hipStream_t stream) {
    const float* x = (const float*)d_in[0];
    const float* qg = (const float*)d_in[1];
    const int* wc = (const int*)d_in[2];
    float* y = (float*)d_out;

    // workspace layout: sx[8192] f32 | sw[4096] f32 | xq[8192*4096] i8 | wq[4096*4096] i8
    const size_t sx_off = 0;
    const size_t sw_off = (size_t)M_DIM * 4;
    const size_t xq_off = (size_t)(M_DIM + N_DIM) * 4;              // 49152
    const size_t wq_off = xq_off + (size_t)M_DIM * K_DIM;
    const size_t need = wq_off + (size_t)N_DIM * K_DIM;

    if (ws_size >= need) {
        float* sx = (float*)((char*)d_ws + sx_off);
        float* sw = (float*)((char*)d_ws + sw_off);
        char* xq = (char*)d_ws + xq_off;
        char* wq = (char*)d_ws + wq_off;
        hipLaunchKernelGGL(quant_x, dim3(M_DIM), dim3(256), 0, stream, x, xq, sx);
        hipLaunchKernelGGL(quant_w, dim3(N_DIM), dim3(256), 0, stream, wc, qg, wq, sw);
        const int nwg = (M_DIM / 256) * (N_DIM / 256);   // 512
        hipLaunchKernelGGL(gemm8, dim3(nwg), dim3(512), 0, stream,
                           xq, wq, sx, sw, y);
    } else {
        hipLaunchKernelGGL(fb_gemm, dim3(N_DIM / 64, M_DIM / 64), dim3(256), 0, stream,
                           x, qg, wc, y);
    }
}